// Round 4
// baseline (130.227 us; speedup 1.0000x reference)
//
#include <hip/hip_runtime.h>

typedef unsigned long long ull;

#define N_PTS   1000000
#define DM      128
#define DP      64
#define RNB     32
#define ENT     32
#define EFS     64
#define KOUT    10
#define N_ITERS 8
#define NTH     1024
#define NWAVE   (NTH / 64)
#define HASHCAP 32768
#define MAXNEW  2048
#define BIGF    1e30f
#define PADKEY  0xFFFFFFFFFFFFFFFFull

__device__ __forceinline__ unsigned fkey_enc(float d) {
  unsigned b = __float_as_uint(d);
  return (b & 0x80000000u) ? ~b : (b | 0x80000000u);
}

// Distance in principal subspace (first 64 dims). Fixed accumulation order;
// BIT-IDENTICAL to rounds 0-3 (absmax was 0.0). Do not perturb.
__device__ __forceinline__ float dist_p(const float* __restrict__ storage,
                                        const float* qf, float qn, int id) {
  int c = id < 0 ? 0 : (id > N_PTS - 1 ? N_PTS - 1 : id);
  const float4* row = (const float4*)(storage + (size_t)c * DM);
  float sq = 0.f, dt = 0.f;
#pragma unroll
  for (int j = 0; j < DP / 4; ++j) {
    float4 s = row[j];
    sq = fmaf(s.x, s.x, sq); sq = fmaf(s.y, s.y, sq);
    sq = fmaf(s.z, s.z, sq); sq = fmaf(s.w, s.w, sq);
    dt = fmaf(s.x, qf[4*j+0], dt); dt = fmaf(s.y, qf[4*j+1], dt);
    dt = fmaf(s.z, qf[4*j+2], dt); dt = fmaf(s.w, qf[4*j+3], dt);
  }
  float d = sq - 2.f * dt + qn;
  return (id >= N_PTS) ? BIGF : d;
}

// Visited-set claim. true => caller evaluates (newly claimed).
// Capacity 32768 > hard insert bound (32 + 8*2048 = 16416): always terminates.
__device__ __forceinline__ bool visit_claim(int* htab, int id) {
  unsigned h = ((unsigned)id * 2654435761u) & (HASHCAP - 1);
  while (true) {
    int cur = htab[h];
    if (cur == id) return false;
    if (cur == -1) {
      int old = atomicCAS(&htab[h], -1, id);
      if (old == -1) return true;
      if (old == id) return false;
    }
    h = (h + 1) & (HASHCAP - 1);
  }
}

// Full bitonic sort of 64 keys held one-per-lane in a wave. Ascending. 21 steps.
__device__ __forceinline__ ull wsort64(ull key, int lane) {
#pragma unroll
  for (int k = 2; k <= 64; k <<= 1) {
#pragma unroll
    for (int j = k >> 1; j > 0; j >>= 1) {
      ull other = __shfl_xor(key, j);
      bool up = ((lane & k) == 0);
      bool lower = ((lane & j) == 0);
      ull mn = key < other ? key : other;
      ull mx = key < other ? other : key;
      key = (up == lower) ? mn : mx;
    }
  }
  return key;
}

// Bitonic 64-seq (one per lane) -> ascending. 6 steps.
__device__ __forceinline__ ull wbmerge64(ull key, int lane) {
#pragma unroll
  for (int j = 32; j > 0; j >>= 1) {
    ull other = __shfl_xor(key, j);
    bool lower = ((lane & j) == 0);
    ull mn = key < other ? key : other;
    ull mx = key < other ? other : key;
    key = lower ? mn : mx;
  }
  return key;
}

// Two ascending sorted 64-seqs -> ascending sorted 64 smallest of the union.
__device__ __forceinline__ ull wmerge(ull a, ull b, int lane) {
  ull brev = __shfl_xor(b, 63);           // b reversed: descending
  ull c = a < brev ? a : brev;            // 64 smallest, bitonic
  return wbmerge64(c, lane);
}

// Wave-aggregated LDS append: one atomic per wave. Returns slot (valid lanes).
__device__ __forceinline__ int wave_append(int* counter, bool want, int lane) {
  ull mask = __ballot(want);
  int pos = -1;
  if (mask) {
    int leader = __ffsll((long long)mask) - 1;
    int base = 0;
    if (lane == leader) base = atomicAdd(counter, (int)__popcll(mask));
    base = __shfl(base, leader);
    pos = base + (int)__popcll(mask & ((1ull << lane) - 1ull));
  }
  return pos;
}

__global__ __launch_bounds__(NTH) void search_kernel(
    const float* __restrict__ query,     // B x 128
    const float* __restrict__ VT,        // 128 x 128
    const float* __restrict__ storage,   // N x 128
    const int*   __restrict__ neighbors, // N x 32
    const int*   __restrict__ entry_ids, // 32
    float* __restrict__ out)             // [B*K ids | B*K dists] as float32
{
  __shared__ int   htab[HASHCAP];        // 128 KB
  __shared__ ull   newkeys[MAXNEW];      // 16 KB
  __shared__ ull   scratch[NWAVE * 64];  // 8 KB: evalids (phase1/2) | wavetop (merge)
  __shared__ ull   beamkey[EFS];
  __shared__ int   beam_id[EFS];
  __shared__ float qf[DM];
  __shared__ float qloc[DM];
  __shared__ float qn_s;
  __shared__ int   nclaim, nc;
  __shared__ float dfull[EFS];

  int* evalids = (int*)scratch;          // capacity 2048 ids

  const int b    = blockIdx.x;
  const int B    = gridDim.x;
  const int tid  = threadIdx.x;
  const int lane = tid & 63;
  const int wid  = tid >> 6;

  const ull FILLKEY = ((ull)fkey_enc(BIGF) << 32) | (unsigned)N_PTS;

  // ---- init visited set ----
  for (int i = tid; i < HASHCAP; i += NTH) htab[i] = -1;

  // ---- q_full = query[b] @ VT.T ----
  if (tid < DM) qloc[tid] = query[(size_t)b * DM + tid];
  __syncthreads();
  if (tid < DM) {
    const float* vrow = VT + (size_t)tid * DM;
    float acc = 0.f;
#pragma unroll 8
    for (int d = 0; d < DM; ++d) acc = fmaf(qloc[d], vrow[d], acc);
    qf[tid] = acc;
  }
  __syncthreads();
  if (tid == 0) {
    float acc = 0.f;
    for (int d = 0; d < DP; ++d) acc = fmaf(qf[d], qf[d], acc);
    qn_s = acc;
  }
  __syncthreads();
  const float qn = qn_s;

  // ---- entry stage: wave 0 only, shuffle sort ----
  if (wid == 0) {
    ull ek = PADKEY;
    if (lane < ENT) {
      int id = entry_ids[lane];
      if (visit_claim(htab, id)) {           // dedups duplicate entry ids
        float d = dist_p(storage, qf, qn, id);
        ek = ((ull)fkey_enc(d) << 32) | (unsigned)id;
      }
    }
    ek = wsort64(ek, lane);
    if (ek == PADKEY) ek = FILLKEY;
    beamkey[lane] = ek;
    beam_id[lane] = (int)(ek & 0xFFFFFFFFull);
  }
  __syncthreads();

  // ---- search iterations ----
  for (int it = 0; it < N_ITERS; ++it) {
    ull kmax = beamkey[EFS - 1];
    if (tid == 0) { nclaim = 0; nc = 0; }
    __syncthreads();

    // phase 1: propose + claim (no gathers), wave-aggregated append
#pragma unroll
    for (int ci = tid; ci < EFS * RNB; ci += NTH) {
      int e = ci >> 5;
      int r = ci & 31;
      int bid = beam_id[e];
      bool want = false;
      int cid = 0;
      if (bid < N_PTS) {
        cid = neighbors[(size_t)bid * RNB + r];
        want = visit_claim(htab, cid);
      }
      int pos = wave_append(&nclaim, want, lane);
      if (want) evalids[pos] = cid;
    }
    __syncthreads();

    // phase 2: pure gather + distance + kmax filter
    int ne = nclaim;
    int ntrips = (ne + NTH - 1) / NTH;
    for (int t = 0; t < ntrips; ++t) {
      int i = t * NTH + tid;
      bool valid = i < ne;
      int cid = valid ? evalids[i] : 0;
      float d = dist_p(storage, qf, qn, cid);
      ull key = ((ull)fkey_enc(d) << 32) | (unsigned)cid;
      bool pass = valid && (key < kmax);
      int pos = wave_append(&nc, pass, lane);
      if (pass) newkeys[pos] = key;
    }
    __syncthreads();

    int cnt = nc;
    if (cnt == 0) break;                     // beam fixed: exact early exit

    // per-wave top-64 over candidate chunks (registers + shuffles only)
    ull tk = PADKEY;
    int nchunks = (cnt + 63) >> 6;
    for (int c = wid; c < nchunks; c += NWAVE) {
      int idx = (c << 6) + lane;
      ull v = (idx < cnt) ? newkeys[idx] : PADKEY;
      v = wsort64(v, lane);
      tk = wmerge(tk, v, lane);
    }
    __syncthreads();                         // evalids dead; reuse as wavetop
    scratch[wid * 64 + lane] = tk;
    __syncthreads();

    // tree merge: 16 -> 8 (waves 0-7), then wave 0 merges 8 + beam
    ull m8 = PADKEY;
    if (wid < 8) {
      ull a  = scratch[(2 * wid) * 64 + lane];
      ull bb = scratch[(2 * wid + 1) * 64 + lane];
      m8 = wmerge(a, bb, lane);
    }
    __syncthreads();
    if (wid < 8) scratch[wid * 64 + lane] = m8;
    __syncthreads();
    if (wid == 0) {
      ull m0 = wmerge(scratch[0 * 64 + lane], scratch[1 * 64 + lane], lane);
      ull m1 = wmerge(scratch[2 * 64 + lane], scratch[3 * 64 + lane], lane);
      ull m2 = wmerge(scratch[4 * 64 + lane], scratch[5 * 64 + lane], lane);
      ull m3 = wmerge(scratch[6 * 64 + lane], scratch[7 * 64 + lane], lane);
      ull t0 = wmerge(m0, m1, lane);
      ull t1 = wmerge(m2, m3, lane);
      ull t2 = wmerge(t0, t1, lane);
      ull nb = wmerge(beamkey[lane], t2, lane);   // all keys distinct
      beamkey[lane] = nb;
      beam_id[lane] = (int)(nb & 0xFFFFFFFFull);
    }
    __syncthreads();
  }

  // ---- final: full 128-dim distances + top-k, wave 0 shuffle sort ----
  if (wid == 0) {
    int id = beam_id[lane];
    int c = id < 0 ? 0 : (id > N_PTS - 1 ? N_PTS - 1 : id);
    const float4* row = (const float4*)(storage + (size_t)c * DM);
    float acc = 0.f;
#pragma unroll
    for (int j = 0; j < DM / 4; ++j) {
      float4 s = row[j];
      float dx = s.x - qf[4*j+0]; acc = fmaf(dx, dx, acc);
      dx = s.y - qf[4*j+1]; acc = fmaf(dx, dx, acc);
      dx = s.z - qf[4*j+2]; acc = fmaf(dx, dx, acc);
      dx = s.w - qf[4*j+3]; acc = fmaf(dx, dx, acc);
    }
    float dv = (id >= N_PTS) ? BIGF : acc;
    dfull[lane] = dv;
    ull fk = ((ull)fkey_enc(dv) << 32) | (unsigned)lane;  // tie-break: position
    fk = wsort64(fk, lane);
    if (lane < KOUT) {
      int pos = (int)(fk & 0xFFFFFFFFull);
      out[(size_t)b * KOUT + lane] = (float)beam_id[pos];
      out[(size_t)B * KOUT + (size_t)b * KOUT + lane] = dfull[pos];
    }
  }
}

extern "C" void kernel_launch(void* const* d_in, const int* in_sizes, int n_in,
                              void* d_out, int out_size, void* d_ws, size_t ws_size,
                              hipStream_t stream) {
  const float* query     = (const float*)d_in[0];
  const float* VT        = (const float*)d_in[1];
  const float* storage   = (const float*)d_in[2];
  const int*   neighbors = (const int*)d_in[3];
  const int*   entry_ids = (const int*)d_in[4];
  float* out = (float*)d_out;

  int B = in_sizes[0] / DM;  // 128
  search_kernel<<<B, NTH, 0, stream>>>(query, VT, storage, neighbors, entry_ids, out);
}